// Round 8
// baseline (61.951 us; speedup 1.0000x reference)
//
#include <hip/hip_runtime.h>

#define C_DIM 19
#define G_DIM 8
#define H_DIM 512
#define W_DIM 512
#define B_DIM 4
#define PLANE (H_DIM * W_DIM)
#define NPIX  (B_DIM * PLANE)
#define NT    256
#define TLX   64
#define TLY   8
#define HXX   (TLX + 2)   // 66
#define HYY   (TLY + 2)   // 10
#define NSTG  ((HYY * HXX + NT - 1) / NT)   // 3 staging iters

__device__ __forceinline__ unsigned bf16rne(float f) {
    unsigned x = __float_as_uint(f);
    return (x + 0x7fffu + ((x >> 16) & 1u)) >> 16;
}
__device__ __forceinline__ float up_lo(unsigned u) { return __uint_as_float(u << 16); }
__device__ __forceinline__ float up_hi(unsigned u) { return __uint_as_float(u & 0xffff0000u); }

// E = softmax(100*matrix over g): E4[c][0]=g0..3, E4[c][1]=g4..7.  NO sync inside.
__device__ __forceinline__ void build_E_nosync(const float* __restrict__ matrix,
                                               float4 (*E4)[2], int tid) {
    if (tid < C_DIM) {
        const int c = tid;
        float m[G_DIM];
        float mx = -1e30f;
        #pragma unroll
        for (int g = 0; g < G_DIM; ++g) {
            m[g] = 100.0f * matrix[g * C_DIM + c];
            mx = fmaxf(mx, m[g]);
        }
        float s = 0.0f;
        #pragma unroll
        for (int g = 0; g < G_DIM; ++g) { m[g] = __expf(m[g] - mx); s += m[g]; }
        const float inv = 1.0f / s;
        E4[c][0] = make_float4(m[0]*inv, m[1]*inv, m[2]*inv, m[3]*inv);
        E4[c][1] = make_float4(m[4]*inv, m[5]*inv, m[6]*inv, m[7]*inv);
    }
}

// ---- K1: softmax over C + encode to G, 2 px/thread; Qg packed [b][h][w][g] bf16 ----
__global__ __launch_bounds__(NT, 4)
void qg_encode(const float* __restrict__ logit,
               const float* __restrict__ matrix,
               uint4* __restrict__ Qg)
{
    __shared__ float4 E4[C_DIM][2];
    build_E_nosync(matrix, E4, threadIdx.x);
    __syncthreads();

    // same XCD-chunked swizzle as K2 so producer/consumer share an XCD L2
    const int bid = blockIdx.x;
    const int swz = (bid & 7) * (NPIX / (2 * NT) / 8) + (bid >> 3);
    const int t   = swz * NT + threadIdx.x;
    const int px0 = t * 2;
    const int b   = px0 >> 18;
    const int pix = px0 & (PLANE - 1);
    const float* __restrict__ p = logit + (size_t)b * C_DIM * PLANE + pix;

    float eg[G_DIM][2];
    #pragma unroll
    for (int g = 0; g < G_DIM; ++g) { eg[g][0] = 0.0f; eg[g][1] = 0.0f; }
    float s0 = 0.0f, s1 = 0.0f;

    #pragma unroll
    for (int c = 0; c < C_DIM; ++c) {
        const float2 lv = *(const float2*)(p + (size_t)c * PLANE);
        const float e0 = __expf(lv.x);
        const float e1 = __expf(lv.y);
        s0 += e0; s1 += e1;
        const float4 E0 = E4[c][0];
        const float4 E1 = E4[c][1];
        eg[0][0] = fmaf(E0.x, e0, eg[0][0]);  eg[0][1] = fmaf(E0.x, e1, eg[0][1]);
        eg[1][0] = fmaf(E0.y, e0, eg[1][0]);  eg[1][1] = fmaf(E0.y, e1, eg[1][1]);
        eg[2][0] = fmaf(E0.z, e0, eg[2][0]);  eg[2][1] = fmaf(E0.z, e1, eg[2][1]);
        eg[3][0] = fmaf(E0.w, e0, eg[3][0]);  eg[3][1] = fmaf(E0.w, e1, eg[3][1]);
        eg[4][0] = fmaf(E1.x, e0, eg[4][0]);  eg[4][1] = fmaf(E1.x, e1, eg[4][1]);
        eg[5][0] = fmaf(E1.y, e0, eg[5][0]);  eg[5][1] = fmaf(E1.y, e1, eg[5][1]);
        eg[6][0] = fmaf(E1.z, e0, eg[6][0]);  eg[6][1] = fmaf(E1.z, e1, eg[6][1]);
        eg[7][0] = fmaf(E1.w, e0, eg[7][0]);  eg[7][1] = fmaf(E1.w, e1, eg[7][1]);
    }
    {
        const float inv = 1.0f / s0;
        uint4 u;
        u.x = bf16rne(eg[0][0]*inv) | (bf16rne(eg[1][0]*inv) << 16);
        u.y = bf16rne(eg[2][0]*inv) | (bf16rne(eg[3][0]*inv) << 16);
        u.z = bf16rne(eg[4][0]*inv) | (bf16rne(eg[5][0]*inv) << 16);
        u.w = bf16rne(eg[6][0]*inv) | (bf16rne(eg[7][0]*inv) << 16);
        Qg[px0] = u;
    }
    {
        const float inv = 1.0f / s1;
        uint4 u;
        u.x = bf16rne(eg[0][1]*inv) | (bf16rne(eg[1][1]*inv) << 16);
        u.y = bf16rne(eg[2][1]*inv) | (bf16rne(eg[3][1]*inv) << 16);
        u.z = bf16rne(eg[4][1]*inv) | (bf16rne(eg[5][1]*inv) << 16);
        u.w = bf16rne(eg[6][1]*inv) | (bf16rne(eg[7][1]*inv) << 16);
        Qg[px0 + 1] = u;
    }
}

// ---- K2: all-loads-up-front LDS-staged 9-tap filter + decode + subtract ----
// grid (8, 64, 4): tile = 64x8 px, 256 threads x 2 px.
__global__ __launch_bounds__(NT, 2)   // VGPR cap 256: keep ALL loads in regs
void crf_decode(const float* __restrict__ F,
                const float* __restrict__ logit,
                const float* __restrict__ matrix,
                const uint4* __restrict__ Qg,
                float* __restrict__ out)
{
    __shared__ float4 E4[C_DIM][2];
    __shared__ uint4  Qs[HYY][HXX];   // 10560 B

    const int tid = threadIdx.x;

    // XCD-chunked bijective swizzle (2048 blocks, 2048 % 8 == 0)
    const int bid = (blockIdx.z * gridDim.y + blockIdx.y) * gridDim.x + blockIdx.x;
    const int swz = (bid & 7) * 256 + (bid >> 3);
    const int b   = swz >> 9;          // 512 tiles per batch
    const int rem = swz & 511;
    const int tby = rem >> 3;          // 0..63
    const int tbx = rem & 7;           // 0..7

    const int tx2 = tid & 31;          // 0..31 (2 px each)
    const int ty  = tid >> 5;          // 0..7
    const int x   = tbx * TLX + tx2 * 2;
    const int y   = tby * TLY + ty;
    const size_t pix = (size_t)y * W_DIM + x;

    // ---- 1. issue Qg staging loads (critical path to barrier) ----
    const int y0 = tby * TLY - 1;
    const int x0 = tbx * TLX - 1;
    const uint4* __restrict__ Qb = Qg + (size_t)b * PLANE;
    uint4 st[NSTG];
    #pragma unroll
    for (int it = 0; it < NSTG; ++it) {
        const int i = tid + it * NT;
        if (i < HYY * HXX) {
            const int r  = i / HXX;
            const int cc = i - r * HXX;
            const int gy = min(max(y0 + r, 0), H_DIM - 1);
            const int gx = min(max(x0 + cc, 0), W_DIM - 1);
            st[it] = Qb[(size_t)gy * W_DIM + gx];
        }
    }

    // ---- 2. issue ALL F loads ----
    const float* __restrict__ Fp = F + (size_t)b * 9 * PLANE + pix;
    float2 wk[9];
    #pragma unroll
    for (int k = 0; k < 9; ++k) wk[k] = *(const float2*)(Fp + (size_t)k * PLANE);

    // ---- 3. issue ALL logit loads ----
    const float* __restrict__ lp = logit + (size_t)b * C_DIM * PLANE + pix;
    float2 lg[C_DIM];
    #pragma unroll
    for (int c = 0; c < C_DIM; ++c) lg[c] = *(const float2*)(lp + (size_t)c * PLANE);

    // ---- E (VALU only, threads 0..18) ----
    build_E_nosync(matrix, E4, tid);

    // ---- 4. LDS writes + barrier ----
    #pragma unroll
    for (int it = 0; it < NSTG; ++it) {
        const int i = tid + it * NT;
        if (i < HYY * HXX) {
            const int r  = i / HXX;
            const int cc = i - r * HXX;
            Qs[r][cc] = st[it];
        }
    }
    __syncthreads();

    // ---- 5. filter from LDS (registers already hold F, logit) ----
    float og[G_DIM][2];
    #pragma unroll
    for (int g = 0; g < G_DIM; ++g) { og[g][0] = 0.0f; og[g][1] = 0.0f; }

    const int lx = tx2 * 2;            // LDS col of (x-1)
    #pragma unroll
    for (int dyi = 0; dyi < 3; ++dyi) {
        const int ry  = y + dyi - 1;
        const bool vy = (ry >= 0) & (ry < H_DIM);
        const uint4 q0 = Qs[ty + dyi][lx];
        const uint4 q1 = Qs[ty + dyi][lx + 1];
        const uint4 q2 = Qs[ty + dyi][lx + 2];
        const uint4 q3 = Qs[ty + dyi][lx + 3];
        const uint4 qv_[4] = {q0, q1, q2, q3};

        #pragma unroll
        for (int dxi = 0; dxi < 3; ++dxi) {
            const int k = dyi * 3 + dxi;
            const float wkv[2] = {wk[k].x, wk[k].y};
            #pragma unroll
            for (int j = 0; j < 2; ++j) {
                const int col = x + j + dxi - 1;
                const bool v = vy & (col >= 0) & (col < W_DIM);
                const float wv = v ? wkv[j] : 0.0f;
                const uint4 qv = qv_[j + dxi];
                og[0][j] = fmaf(wv, up_lo(qv.x), og[0][j]);
                og[1][j] = fmaf(wv, up_hi(qv.x), og[1][j]);
                og[2][j] = fmaf(wv, up_lo(qv.y), og[2][j]);
                og[3][j] = fmaf(wv, up_hi(qv.y), og[3][j]);
                og[4][j] = fmaf(wv, up_lo(qv.z), og[4][j]);
                og[5][j] = fmaf(wv, up_hi(qv.z), og[5][j]);
                og[6][j] = fmaf(wv, up_lo(qv.w), og[6][j]);
                og[7][j] = fmaf(wv, up_hi(qv.w), og[7][j]);
            }
        }
    }

    // ---- 6. decode + subtract + store (logit already in regs) ----
    float* __restrict__ op = out + (size_t)b * C_DIM * PLANE + pix;
    #pragma unroll
    for (int c = 0; c < C_DIM; ++c) {
        const float4 E0 = E4[c][0];
        const float4 E1 = E4[c][1];
        float d[2];
        #pragma unroll
        for (int j = 0; j < 2; ++j) {
            float dec = og[0][j] * E0.x;
            dec = fmaf(og[1][j], E0.y, dec);
            dec = fmaf(og[2][j], E0.z, dec);
            dec = fmaf(og[3][j], E0.w, dec);
            dec = fmaf(og[4][j], E1.x, dec);
            dec = fmaf(og[5][j], E1.y, dec);
            dec = fmaf(og[6][j], E1.z, dec);
            dec = fmaf(og[7][j], E1.w, dec);
            d[j] = dec;
        }
        float2 o;
        o.x = lg[c].x - d[0];
        o.y = lg[c].y - d[1];
        *(float2*)(op + (size_t)c * PLANE) = o;
    }
}

extern "C" void kernel_launch(void* const* d_in, const int* in_sizes, int n_in,
                              void* d_out, int out_size, void* d_ws, size_t ws_size,
                              hipStream_t stream) {
    const float* F      = (const float*)d_in[0];   // [4, 9, 512, 512]
    const float* logit  = (const float*)d_in[1];   // [4, 19, 512, 512]
    const float* matrix = (const float*)d_in[2];   // [8, 19, 1, 1]
    float* out = (float*)d_out;                    // [4, 19, 512, 512]
    uint4* Qg = (uint4*)d_ws;                      // 16.8 MB: [4][512][512] x 8 bf16

    qg_encode <<<NPIX / (2 * NT), NT, 0, stream>>>(logit, matrix, Qg);
    dim3 grid2(W_DIM / TLX, H_DIM / TLY, B_DIM);   // (8, 64, 4) = 2048
    crf_decode<<<grid2, NT, 0, stream>>>(F, logit, matrix, Qg, out);
}

// Round 9
// 52.459 us; speedup vs baseline: 1.1809x; 1.1809x over previous
//
#include <hip/hip_runtime.h>

#define C_DIM 19
#define G_DIM 8
#define H_DIM 512
#define W_DIM 512
#define B_DIM 4
#define PLANE (H_DIM * W_DIM)
#define NPIX  (B_DIM * PLANE)
#define NT    256
#define TLX   64
#define TLY   8
#define HXX   (TLX + 2)   // 66
#define HYY   (TLY + 2)   // 10

__device__ __forceinline__ unsigned bf16rne(float f) {
    unsigned x = __float_as_uint(f);
    return (x + 0x7fffu + ((x >> 16) & 1u)) >> 16;
}
__device__ __forceinline__ float up_lo(unsigned u) { return __uint_as_float(u << 16); }
__device__ __forceinline__ float up_hi(unsigned u) { return __uint_as_float(u & 0xffff0000u); }

__device__ __forceinline__ float2 ntload2(const float* p) {
    unsigned long long v = __builtin_nontemporal_load((const unsigned long long*)p);
    float2 r;
    r.x = __uint_as_float((unsigned)v);
    r.y = __uint_as_float((unsigned)(v >> 32));
    return r;
}
__device__ __forceinline__ void ntstore2(float* p, float f0, float f1) {
    unsigned long long v = (unsigned long long)__float_as_uint(f0) |
                           ((unsigned long long)__float_as_uint(f1) << 32);
    __builtin_nontemporal_store(v, (unsigned long long*)p);
}

// E = softmax(100*matrix over g): E4[c][0]=g0..3, E4[c][1]=g4..7.  NO sync inside.
__device__ __forceinline__ void build_E_nosync(const float* __restrict__ matrix,
                                               float4 (*E4)[2], int tid) {
    if (tid < C_DIM) {
        const int c = tid;
        float m[G_DIM];
        float mx = -1e30f;
        #pragma unroll
        for (int g = 0; g < G_DIM; ++g) {
            m[g] = 100.0f * matrix[g * C_DIM + c];
            mx = fmaxf(mx, m[g]);
        }
        float s = 0.0f;
        #pragma unroll
        for (int g = 0; g < G_DIM; ++g) { m[g] = __expf(m[g] - mx); s += m[g]; }
        const float inv = 1.0f / s;
        E4[c][0] = make_float4(m[0]*inv, m[1]*inv, m[2]*inv, m[3]*inv);
        E4[c][1] = make_float4(m[4]*inv, m[5]*inv, m[6]*inv, m[7]*inv);
    }
}

// ---- K1: softmax over C + encode to G, 2 px/thread; Qg packed [b][h][w][g] bf16 ----
__global__ __launch_bounds__(NT, 4)
void qg_encode(const float* __restrict__ logit,
               const float* __restrict__ matrix,
               uint4* __restrict__ Qg)
{
    __shared__ float4 E4[C_DIM][2];
    build_E_nosync(matrix, E4, threadIdx.x);
    __syncthreads();

    // same XCD-chunked swizzle as K2 so producer/consumer share an XCD L2
    const int bid = blockIdx.x;
    const int swz = (bid & 7) * (NPIX / (2 * NT) / 8) + (bid >> 3);
    const int t   = swz * NT + threadIdx.x;
    const int px0 = t * 2;
    const int b   = px0 >> 18;
    const int pix = px0 & (PLANE - 1);
    const float* __restrict__ p = logit + (size_t)b * C_DIM * PLANE + pix;

    float eg[G_DIM][2];
    #pragma unroll
    for (int g = 0; g < G_DIM; ++g) { eg[g][0] = 0.0f; eg[g][1] = 0.0f; }
    float s0 = 0.0f, s1 = 0.0f;

    #pragma unroll
    for (int c = 0; c < C_DIM; ++c) {
        const float2 lv = *(const float2*)(p + (size_t)c * PLANE);
        const float e0 = __expf(lv.x);
        const float e1 = __expf(lv.y);
        s0 += e0; s1 += e1;
        const float4 E0 = E4[c][0];
        const float4 E1 = E4[c][1];
        eg[0][0] = fmaf(E0.x, e0, eg[0][0]);  eg[0][1] = fmaf(E0.x, e1, eg[0][1]);
        eg[1][0] = fmaf(E0.y, e0, eg[1][0]);  eg[1][1] = fmaf(E0.y, e1, eg[1][1]);
        eg[2][0] = fmaf(E0.z, e0, eg[2][0]);  eg[2][1] = fmaf(E0.z, e1, eg[2][1]);
        eg[3][0] = fmaf(E0.w, e0, eg[3][0]);  eg[3][1] = fmaf(E0.w, e1, eg[3][1]);
        eg[4][0] = fmaf(E1.x, e0, eg[4][0]);  eg[4][1] = fmaf(E1.x, e1, eg[4][1]);
        eg[5][0] = fmaf(E1.y, e0, eg[5][0]);  eg[5][1] = fmaf(E1.y, e1, eg[5][1]);
        eg[6][0] = fmaf(E1.z, e0, eg[6][0]);  eg[6][1] = fmaf(E1.z, e1, eg[6][1]);
        eg[7][0] = fmaf(E1.w, e0, eg[7][0]);  eg[7][1] = fmaf(E1.w, e1, eg[7][1]);
    }
    {
        const float inv = 1.0f / s0;
        uint4 u;
        u.x = bf16rne(eg[0][0]*inv) | (bf16rne(eg[1][0]*inv) << 16);
        u.y = bf16rne(eg[2][0]*inv) | (bf16rne(eg[3][0]*inv) << 16);
        u.z = bf16rne(eg[4][0]*inv) | (bf16rne(eg[5][0]*inv) << 16);
        u.w = bf16rne(eg[6][0]*inv) | (bf16rne(eg[7][0]*inv) << 16);
        Qg[px0] = u;
    }
    {
        const float inv = 1.0f / s1;
        uint4 u;
        u.x = bf16rne(eg[0][1]*inv) | (bf16rne(eg[1][1]*inv) << 16);
        u.y = bf16rne(eg[2][1]*inv) | (bf16rne(eg[3][1]*inv) << 16);
        u.z = bf16rne(eg[4][1]*inv) | (bf16rne(eg[5][1]*inv) << 16);
        u.w = bf16rne(eg[6][1]*inv) | (bf16rne(eg[7][1]*inv) << 16);
        Qg[px0 + 1] = u;
    }
}

// ---- K2: LDS-staged 9-tap filter + pipelined decode + nt-store, 2 px/thread ----
// grid (8, 64, 4): tile = 64x8 px, 256 threads x 2 px.
__global__ __launch_bounds__(NT, 4)
void crf_decode(const float* __restrict__ F,
                const float* __restrict__ logit,
                const float* __restrict__ matrix,
                const uint4* __restrict__ Qg,
                float* __restrict__ out)
{
    __shared__ float4 E4[C_DIM][2];
    __shared__ uint4  Qs[HYY][HXX];   // 10560 B

    const int tid = threadIdx.x;
    build_E_nosync(matrix, E4, tid);

    // XCD-chunked bijective swizzle (2048 blocks, 2048 % 8 == 0)
    const int bid = (blockIdx.z * gridDim.y + blockIdx.y) * gridDim.x + blockIdx.x;
    const int swz = (bid & 7) * 256 + (bid >> 3);
    const int b   = swz >> 9;          // 512 tiles per batch
    const int rem = swz & 511;
    const int tby = rem >> 3;          // 0..63
    const int tbx = rem & 7;           // 0..7

    const int tx2 = tid & 31;          // 0..31 (2 px each)
    const int ty  = tid >> 5;          // 0..7
    const int x   = tbx * TLX + tx2 * 2;
    const int y   = tby * TLY + ty;
    const size_t pix = (size_t)y * W_DIM + x;

    // F loads (nontemporal, read-once): issued early, arrive by the barrier drain
    const float* __restrict__ Fp = F + (size_t)b * 9 * PLANE + pix;
    float2 wk[9];
    #pragma unroll
    for (int k = 0; k < 9; ++k) wk[k] = ntload2(Fp + (size_t)k * PLANE);

    // stage Qg halo tile (clamped) into LDS, coalesced rows
    const int y0 = tby * TLY - 1;
    const int x0 = tbx * TLX - 1;
    const uint4* __restrict__ Qb = Qg + (size_t)b * PLANE;
    #pragma unroll
    for (int it = 0; it < 3; ++it) {
        const int i = tid + it * NT;
        if (i < HYY * HXX) {
            const int r  = i / HXX;
            const int cc = i - r * HXX;
            const int gy = min(max(y0 + r, 0), H_DIM - 1);
            const int gx = min(max(x0 + cc, 0), W_DIM - 1);
            Qs[r][cc] = Qb[(size_t)gy * W_DIM + gx];
        }
    }
    __syncthreads();

    // issue first 8 logit loads now; filter phase (~300 cyc VALU/LDS) covers them
    const float* __restrict__ lp = logit + (size_t)b * C_DIM * PLANE + pix;
    float2 l0 = *(const float2*)(lp + 0 * (size_t)PLANE);
    float2 l1 = *(const float2*)(lp + 1 * (size_t)PLANE);
    float2 l2 = *(const float2*)(lp + 2 * (size_t)PLANE);
    float2 l3 = *(const float2*)(lp + 3 * (size_t)PLANE);
    float2 l4 = *(const float2*)(lp + 4 * (size_t)PLANE);
    float2 l5 = *(const float2*)(lp + 5 * (size_t)PLANE);
    float2 l6 = *(const float2*)(lp + 6 * (size_t)PLANE);
    float2 l7 = *(const float2*)(lp + 7 * (size_t)PLANE);

    // filter from LDS
    float og[G_DIM][2];
    #pragma unroll
    for (int g = 0; g < G_DIM; ++g) { og[g][0] = 0.0f; og[g][1] = 0.0f; }

    const int lx = tx2 * 2;            // LDS col of (x-1)
    #pragma unroll
    for (int dyi = 0; dyi < 3; ++dyi) {
        const int ry  = y + dyi - 1;
        const bool vy = (ry >= 0) & (ry < H_DIM);
        const uint4 q0 = Qs[ty + dyi][lx];
        const uint4 q1 = Qs[ty + dyi][lx + 1];
        const uint4 q2 = Qs[ty + dyi][lx + 2];
        const uint4 q3 = Qs[ty + dyi][lx + 3];
        const uint4 qv_[4] = {q0, q1, q2, q3};

        #pragma unroll
        for (int dxi = 0; dxi < 3; ++dxi) {
            const int k = dyi * 3 + dxi;
            const float wkv[2] = {wk[k].x, wk[k].y};
            #pragma unroll
            for (int j = 0; j < 2; ++j) {
                const int col = x + j + dxi - 1;
                const bool v = vy & (col >= 0) & (col < W_DIM);
                const float wv = v ? wkv[j] : 0.0f;
                const uint4 qv = qv_[j + dxi];
                og[0][j] = fmaf(wv, up_lo(qv.x), og[0][j]);
                og[1][j] = fmaf(wv, up_hi(qv.x), og[1][j]);
                og[2][j] = fmaf(wv, up_lo(qv.y), og[2][j]);
                og[3][j] = fmaf(wv, up_hi(qv.y), og[3][j]);
                og[4][j] = fmaf(wv, up_lo(qv.z), og[4][j]);
                og[5][j] = fmaf(wv, up_hi(qv.z), og[5][j]);
                og[6][j] = fmaf(wv, up_lo(qv.w), og[6][j]);
                og[7][j] = fmaf(wv, up_hi(qv.w), og[7][j]);
            }
        }
    }

    // decode + subtract + nt-store, depth-8 rotating load pipeline
    float* __restrict__ op = out + (size_t)b * C_DIM * PLANE + pix;
    #pragma unroll
    for (int c = 0; c < C_DIM; ++c) {
        const float2 cur = l0;
        l0 = l1; l1 = l2; l2 = l3; l3 = l4; l4 = l5; l5 = l6; l6 = l7;
        if (c + 8 < C_DIM)
            l7 = *(const float2*)(lp + (size_t)(c + 8) * PLANE);

        const float4 E0 = E4[c][0];
        const float4 E1 = E4[c][1];
        float d0 = og[0][0] * E0.x;
        float d1 = og[0][1] * E0.x;
        d0 = fmaf(og[1][0], E0.y, d0);  d1 = fmaf(og[1][1], E0.y, d1);
        d0 = fmaf(og[2][0], E0.z, d0);  d1 = fmaf(og[2][1], E0.z, d1);
        d0 = fmaf(og[3][0], E0.w, d0);  d1 = fmaf(og[3][1], E0.w, d1);
        d0 = fmaf(og[4][0], E1.x, d0);  d1 = fmaf(og[4][1], E1.x, d1);
        d0 = fmaf(og[5][0], E1.y, d0);  d1 = fmaf(og[5][1], E1.y, d1);
        d0 = fmaf(og[6][0], E1.z, d0);  d1 = fmaf(og[6][1], E1.z, d1);
        d0 = fmaf(og[7][0], E1.w, d0);  d1 = fmaf(og[7][1], E1.w, d1);

        ntstore2(op + (size_t)c * PLANE, cur.x - d0, cur.y - d1);
    }
}

extern "C" void kernel_launch(void* const* d_in, const int* in_sizes, int n_in,
                              void* d_out, int out_size, void* d_ws, size_t ws_size,
                              hipStream_t stream) {
    const float* F      = (const float*)d_in[0];   // [4, 9, 512, 512]
    const float* logit  = (const float*)d_in[1];   // [4, 19, 512, 512]
    const float* matrix = (const float*)d_in[2];   // [8, 19, 1, 1]
    float* out = (float*)d_out;                    // [4, 19, 512, 512]
    uint4* Qg = (uint4*)d_ws;                      // 16.8 MB: [4][512][512] x 8 bf16

    qg_encode <<<NPIX / (2 * NT), NT, 0, stream>>>(logit, matrix, Qg);
    dim3 grid2(W_DIM / TLX, H_DIM / TLY, B_DIM);   // (8, 64, 4) = 2048
    crf_decode<<<grid2, NT, 0, stream>>>(F, logit, matrix, Qg, out);
}